// Round 16
// baseline (193.403 us; speedup 1.0000x reference)
//
#include <hip/hip_runtime.h>
#include <hip/hip_bf16.h>
#include <cstdint>

#define NEGV (-10000.0f)

typedef short bf16x8 __attribute__((ext_vector_type(8)));
typedef short bf16x4 __attribute__((ext_vector_type(4)));
typedef float f32x4 __attribute__((ext_vector_type(4)));

__device__ __forceinline__ short f2bf(float f) {
  union { float f; uint32_t u; } v; v.f = f;
  uint32_t u = v.u + 0x7fffu + ((v.u >> 16) & 1u);
  return (short)(u >> 16);
}
__device__ __forceinline__ float b2f(short s) {
  union { uint32_t u; float f; } v; v.u = ((uint32_t)(uint16_t)s) << 16;
  return v.f;
}
__device__ __forceinline__ uint32_t pk2(float lo, float hi) {
  union { __hip_bfloat162 h2; uint32_t u; } cv;
  cv.h2.x = __float2bfloat16(lo);
  cv.h2.y = __float2bfloat16(hi);
  return cv.u;
}

// LDS-only barrier: no vmcnt drain; ring prefetch loads survive barriers.
__device__ __forceinline__ void bar() {
  __builtin_amdgcn_sched_barrier(0);
  asm volatile("s_waitcnt lgkmcnt(0)" ::: "memory");
  __builtin_amdgcn_s_barrier();
  __builtin_amdgcn_sched_barrier(0);
}

// ---------------- P1: weight combine + bf16 casts ----------------
__global__ void prep_weights(const float* __restrict__ W1, const float* __restrict__ W2,
                             short* __restrict__ Wk, short* __restrict__ Wd,
                             short* __restrict__ W2b) {
  int idx = blockIdx.x * 256 + threadIdx.x;
  if (idx < 32768) {
    int h = idx >> 7, d = idx & 127;
    Wk[idx] = f2bf(W1[h * 512 + 128 + d] - W1[h * 512 + 256 + d]);
  } else if (idx < 65536) {
    int i = idx - 32768;
    int h = i >> 7, d = i & 127;
    Wd[i] = f2bf(W1[h * 512 + 384 + d]);
  } else {
    int i = idx - 65536;
    W2b[i] = f2bf(W2[i]);
  }
}

// ---------------- P2: U[b][h] = b1[h] + sum_d (W1[h][d]+W1[h][256+d]) * q[b][d] ----
__global__ void prep_u(const float* __restrict__ query, const float* __restrict__ W1,
                       const float* __restrict__ b1, float* __restrict__ U) {
  __shared__ float q8[8][128];
  int tid = threadIdx.x;
  int b0 = blockIdx.x * 8;
  for (int i = tid; i < 1024; i += 256)
    q8[i >> 7][i & 127] = query[(size_t)(b0 + (i >> 7)) * 128 + (i & 127)];
  __syncthreads();
  int h = tid;
  const float4* w0 = (const float4*)(W1 + (size_t)h * 512);
  const float4* w1 = (const float4*)(W1 + (size_t)h * 512 + 256);
  float acc[8];
  float bb = b1[h];
#pragma unroll
  for (int i = 0; i < 8; ++i) acc[i] = bb;
  for (int d4 = 0; d4 < 32; ++d4) {
    float4 wa = w0[d4], wb = w1[d4];
    float wv0 = wa.x + wb.x, wv1 = wa.y + wb.y, wv2 = wa.z + wb.z, wv3 = wa.w + wb.w;
#pragma unroll
    for (int i = 0; i < 8; ++i) {
      float4 qv = ((const float4*)q8[i])[d4];
      acc[i] += wv0 * qv.x + wv1 * qv.y + wv2 * qv.z + wv3 * qv.w;
    }
  }
#pragma unroll
  for (int i = 0; i < 8; ++i) U[(size_t)(b0 + i) * 256 + h] = acc[i];
}

// ---------------- fused main: one 1024-thr block per b, balanced 16 waves ----
// R16: every wave does GEMM1 (16 h, mf=16 VGPR) AND GEMM2 (one 16g x 16l tile,
// w2f=32 VGPR) each phase; 32-l tiles; R14 pipelining (GEMM2(t-1) || GEMM1(t));
// 1 bar/phase; keys write-once in Kall -> fused tail reads LDS (FETCH halves).
__global__ __launch_bounds__(1024) void din_fused(
    const float* __restrict__ query, const float* __restrict__ keys,
    const int* __restrict__ mask,
    const float* __restrict__ b2p, const float* __restrict__ a1p,
    const float* __restrict__ a2p, const float* __restrict__ W3,
    const float* __restrict__ U, const short* __restrict__ Wk,
    const short* __restrict__ Wd, const short* __restrict__ W2b,
    float* __restrict__ out) {
  __shared__ short Kall[224 * 128];       // 57.3 KB bf16 keys, XOR-swizzled, write-once
  __shared__ union {
    short H1[2][32 * 256];                // 32 KB h1 dbuf [l][h], XOR-swizzled
    float opart[64][128];                 // wsum partials (disjoint lifetime)
  } uH;
  __shared__ float wred[8][224];          // 7 KB per-g-tile score partials
  __shared__ float wl[224];
  __shared__ float Ul[256];
  __shared__ float red[32];

  const int tid = threadIdx.x;
  const int b = blockIdx.x;
  const int lane = tid & 63, wid = tid >> 6;   // 16 waves
  const int lr = lane & 15, lg = lane >> 4;
  const int gt = wid >> 1, lh = wid & 1;       // GEMM2 tile: g-tile, l-half
  const int sw = (lr & 7) << 3;

  const float a1 = a1p[0], a2 = a2p[0];

  if (tid < 256) Ul[tid] = U[(size_t)b * 256 + tid];

  // ---- persistent fragments (per wave) ----
  bf16x8 mf[4];     // GEMM1 A: M_b[h=wid*16+lr][k], 16 VGPR
  {
    const float* qrow = query + (size_t)b * 128;
    int h = wid * 16 + lr;
#pragma unroll
    for (int ks = 0; ks < 4; ++ks) {
      int d0 = ks * 32 + lg * 8;
      bf16x8 wk = *(const bf16x8*)(Wk + h * 128 + d0);
      bf16x8 wd = *(const bf16x8*)(Wd + h * 128 + d0);
      float4 q0 = *(const float4*)(qrow + d0);
      float4 q1 = *(const float4*)(qrow + d0 + 4);
      float qv[8] = {q0.x, q0.y, q0.z, q0.w, q1.x, q1.y, q1.z, q1.w};
      float mv[8];
#pragma unroll
      for (int j = 0; j < 8; ++j) mv[j] = b2f(wk[j]) + b2f(wd[j]) * qv[j];
      union { bf16x8 v; uint32_t u[4]; } mm;
#pragma unroll
      for (int j = 0; j < 4; ++j) mm.u[j] = pk2(mv[2 * j], mv[2 * j + 1]);
      mf[ks] = mm.v;
    }
  }
  bf16x8 w2f[8];    // GEMM2 A: W2[g=gt*16+lr][k], 32 VGPR
  {
    int g = gt * 16 + lr;
#pragma unroll
    for (int ks = 0; ks < 8; ++ks)
      w2f[ks] = *(const bf16x8*)(W2b + g * 256 + ks * 32 + lg * 8);
  }
  float uv[4], b2v[4], w3v[4];
#pragma unroll
  for (int r = 0; r < 4; ++r) {
    uv[r] = U[(size_t)b * 256 + wid * 16 + lg * 4 + r];
    int gg = gt * 16 + lg * 4 + r;
    b2v[r] = b2p[gg];
    w3v[r] = W3[gg];
  }

  // staging geometry: 1024 thr, 32 rows/tile, 32 thr/row, float4 each
  const int srow = tid >> 5;            // 0..31
  const int sc4 = (tid & 31) * 4;       // f32/short col 0..124
  const int ssw = (srow & 7) << 3;

  float4 rg;                            // ring hold (tile p+2)
  {
    // tiles 0,1 staged direct (rows 0..63 valid)
#pragma unroll
    for (int t = 0; t < 2; ++t) {
      int grow = t * 32 + srow;
      float4 x = *(const float4*)(keys + ((size_t)b * 200 + grow) * 128 + sc4);
      union { bf16x4 v; uint32_t u[2]; } w;
      w.u[0] = pk2(x.x, x.y); w.u[1] = pk2(x.z, x.w);
      *(bf16x4*)(&Kall[grow * 128 + (sc4 ^ ssw)]) = w.v;
    }
    // tile 2 into ring (rows 64..95 valid)
    rg = *(const float4*)(keys + ((size_t)b * 200 + 64 + srow) * 128 + sc4);
  }
  bar();

  // ---- 8 phases: GEMM1 on tile p (p<7) || GEMM2 on tile p-1 (p>=1) ----
  for (int p = 0; p < 8; ++p) {
    const int buf = p & 1;

    // ring issue: loads for tile p+3 (held one phase, survive bar())
    float4 nrg;
    if (p <= 3) {
      int grow = (p + 3) * 32 + srow;
      nrg = make_float4(0.f, 0.f, 0.f, 0.f);
      if (grow < 200)
        nrg = *(const float4*)(keys + ((size_t)b * 200 + grow) * 128 + sc4);
    }

    // ---- GEMM2 on tile p-1: one 16g x 16l tile per wave, K=256 ----
    if (p >= 1) {
      const short* hr = &uH.H1[buf ^ 1][(lh * 16 + lr) * 256];
      f32x4 acc2;
#pragma unroll
      for (int r = 0; r < 4; ++r) acc2[r] = b2v[r];
      __builtin_amdgcn_s_setprio(1);
#pragma unroll
      for (int ks = 0; ks < 8; ++ks) {
        bf16x8 hf = *(const bf16x8*)(&hr[(ks * 32 + lg * 8) ^ sw]);
        acc2 = __builtin_amdgcn_mfma_f32_16x16x32_bf16(w2f[ks], hf, acc2, 0, 0, 0);
      }
      __builtin_amdgcn_s_setprio(0);
      float s = 0.f;
#pragma unroll
      for (int r = 0; r < 4; ++r) {
        float v = acc2[r];
        v = (v >= 0.f) ? v : a2 * v;
        s += v * w3v[r];
      }
      s += __shfl_xor(s, 16);
      s += __shfl_xor(s, 32);
      if (lg == 0) wred[gt][(p - 1) * 32 + lh * 16 + lr] = s;
    }

    // ---- GEMM1 on tile p: 16 h x 32 l per wave (2 l-halves) ----
    if (p < 7) {
      short* h1b = uH.H1[buf];
#pragma unroll
      for (int s2 = 0; s2 < 2; ++s2) {
        const int lrow = p * 32 + s2 * 16 + lr;
        bf16x8 kf[4];
#pragma unroll
        for (int ks = 0; ks < 4; ++ks)
          kf[ks] = *(const bf16x8*)(&Kall[lrow * 128 + ((ks * 32 + lg * 8) ^ sw)]);
        f32x4 acc;
#pragma unroll
        for (int r = 0; r < 4; ++r) acc[r] = uv[r];
        __builtin_amdgcn_s_setprio(1);
#pragma unroll
        for (int ks = 0; ks < 4; ++ks)
          acc = __builtin_amdgcn_mfma_f32_16x16x32_bf16(mf[ks], kf[ks], acc, 0, 0, 0);
        __builtin_amdgcn_s_setprio(0);
        float v0 = acc[0], v1 = acc[1], v2 = acc[2], v3 = acc[3];
        v0 = (v0 >= 0.f) ? v0 : a1 * v0;
        v1 = (v1 >= 0.f) ? v1 : a1 * v1;
        v2 = (v2 >= 0.f) ? v2 : a1 * v2;
        v3 = (v3 >= 0.f) ? v3 : a1 * v3;
        union { bf16x4 v; uint32_t u[2]; } hh;
        hh.u[0] = pk2(v0, v1); hh.u[1] = pk2(v2, v3);
        *(bf16x4*)(&h1b[(s2 * 16 + lr) * 256 + ((wid * 16 + lg * 4) ^ sw)]) = hh.v;
      }
    }

    // ring write: tile p+2 -> Kall (write-once rows; loads ~1 phase old)
    if (p <= 4) {
      int grow = (p + 2) * 32 + srow;
      union { bf16x4 v; uint32_t u[2]; } w;
      w.u[0] = pk2(rg.x, rg.y); w.u[1] = pk2(rg.z, rg.w);
      *(bf16x4*)(&Kall[grow * 128 + (sc4 ^ ssw)]) = w.v;
    }
    if (p <= 3) rg = nrg;

    bar();  // the ONLY barrier per phase
  }

  // ---- score merge ----
  if (tid < 224) {
    float s = 0.f;
#pragma unroll
    for (int w = 0; w < 8; ++w) s += wred[w][tid];
    wl[tid] = s;
  }
  bar();

  // ---- masked softmax over l=0..199 ----
  float val = NEGV;
  int mk = 0;
  if (tid < 200) {
    mk = mask[(size_t)b * 200 + tid];
    val = mk ? wl[tid] : NEGV;
  }
  float m = val;
#pragma unroll
  for (int off = 1; off < 64; off <<= 1) m = fmaxf(m, __shfl_xor(m, off));
  if (lane == 0) red[wid] = m;
  bar();
  float smax = red[0];
#pragma unroll
  for (int i = 1; i < 16; ++i) smax = fmaxf(smax, red[i]);
  float pex = (tid < 200 && mk) ? __expf(val - smax) : 0.f;
  float s = pex;
#pragma unroll
  for (int off = 1; off < 64; off <<= 1) s += __shfl_xor(s, off);
  if (lane == 0) red[16 + wid] = s;
  bar();
  float ssum = 0.f;
#pragma unroll
  for (int i = 0; i < 16; ++i) ssum += red[16 + i];
  float winv = (ssum > 0.f) ? 1.f / ssum : 0.f;
  if (tid < 224) wl[tid] = (tid < 200) ? pex * winv : 0.f;
  bar();

  // ---- weighted sum from LDS bf16 keys (vectorized bf16x8) ----
  {
    const int d0 = (tid & 15) * 8;      // 8 d's per thread
    const int slice = tid >> 4;         // 0..63
    float a[8];
#pragma unroll
    for (int j = 0; j < 8; ++j) a[j] = 0.f;
    for (int l = slice; l < 200; l += 64) {
      float wv = wl[l];
      bf16x8 kv = *(const bf16x8*)(&Kall[l * 128 + (d0 ^ ((l & 7) << 3))]);
#pragma unroll
      for (int j = 0; j < 8; ++j) a[j] += wv * b2f(kv[j]);
    }
    bar();  // H1 reads all done (GEMM2 drained); opart may overwrite
    *(float4*)(&uH.opart[slice][d0]) = make_float4(a[0], a[1], a[2], a[3]);
    *(float4*)(&uH.opart[slice][d0 + 4]) = make_float4(a[4], a[5], a[6], a[7]);
  }
  bar();
  if (tid < 128) {
    float acc = 0.f;
#pragma unroll
    for (int i = 0; i < 64; ++i) acc += uH.opart[i][tid];
    out[(size_t)b * 128 + tid] = acc;
  }
}

extern "C" void kernel_launch(void* const* d_in, const int* in_sizes, int n_in,
                              void* d_out, int out_size, void* d_ws, size_t ws_size,
                              hipStream_t stream) {
  const float* query = (const float*)d_in[0];
  const float* keys  = (const float*)d_in[1];
  const int*   maskp = (const int*)d_in[2];
  const float* W1    = (const float*)d_in[3];
  const float* b1    = (const float*)d_in[4];
  const float* a1    = (const float*)d_in[5];
  const float* W2    = (const float*)d_in[6];
  const float* b2    = (const float*)d_in[7];
  const float* a2    = (const float*)d_in[8];
  const float* W3    = (const float*)d_in[9];
  float* out = (float*)d_out;

  float* U   = (float*)d_ws;                         // 2 MiB
  short* Wk  = (short*)((char*)d_ws + 2097152);      // 64 KiB
  short* Wd  = Wk + 32768;                           // 64 KiB
  short* W2b = Wd + 32768;                           // 64 KiB

  prep_weights<<<384, 256, 0, stream>>>(W1, W2, Wk, Wd, W2b);
  prep_u<<<256, 256, 0, stream>>>(query, W1, b1, U);
  din_fused<<<2048, 1024, 0, stream>>>(query, keys, maskp, b2, a1, a2, W3,
                                       U, Wk, Wd, W2b, out);
}